// Round 2
// baseline (189.228 us; speedup 1.0000x reference)
//
#include <hip/hip_runtime.h>
#include <cstddef>

// DCT-II matrix (float32 cast of numpy's float64 values)
static constexpr float D8[8][8] = {
  { 0.35355339059327373f, 0.35355339059327373f, 0.35355339059327373f, 0.35355339059327373f,
    0.35355339059327373f, 0.35355339059327373f, 0.35355339059327373f, 0.35355339059327373f},
  { 0.4903926402016152f,  0.4157348061512726f,  0.27778511650980114f, 0.09754516100806417f,
   -0.09754516100806417f,-0.27778511650980114f,-0.4157348061512726f, -0.4903926402016152f},
  { 0.46193976625564337f, 0.19134171618254492f,-0.19134171618254492f,-0.46193976625564337f,
   -0.46193976625564337f,-0.19134171618254492f, 0.19134171618254492f, 0.46193976625564337f},
  { 0.4157348061512726f, -0.09754516100806417f,-0.4903926402016152f, -0.27778511650980114f,
    0.27778511650980114f, 0.4903926402016152f,  0.09754516100806417f,-0.4157348061512726f},
  { 0.35355339059327373f,-0.35355339059327373f,-0.35355339059327373f, 0.35355339059327373f,
    0.35355339059327373f,-0.35355339059327373f,-0.35355339059327373f, 0.35355339059327373f},
  { 0.27778511650980114f,-0.4903926402016152f,  0.09754516100806417f, 0.4157348061512726f,
   -0.4157348061512726f, -0.09754516100806417f, 0.4903926402016152f, -0.27778511650980114f},
  { 0.19134171618254492f,-0.46193976625564337f, 0.46193976625564337f,-0.19134171618254492f,
   -0.19134171618254492f, 0.46193976625564337f,-0.46193976625564337f, 0.19134171618254492f},
  { 0.09754516100806417f,-0.27778511650980114f, 0.4157348061512726f, -0.4903926402016152f,
    0.4903926402016152f, -0.4157348061512726f,  0.27778511650980114f,-0.09754516100806417f},
};

// Quality-95 quant tables: q = clamp(floor((base*10+50)/100), 1, 255)
static constexpr float QLt[8][8] = {
  {2,1,1,2,2,4,5,6},
  {1,1,1,2,3,6,6,6},
  {1,1,2,2,4,6,7,6},
  {1,2,2,3,5,9,8,6},
  {2,2,4,6,7,11,10,8},
  {2,4,6,6,8,10,11,9},
  {5,6,8,9,10,12,12,10},
  {7,9,10,10,11,10,10,10},
};
static constexpr float QCt[8][8] = {
  {2,2,2,5,10,10,10,10},
  {2,2,3,7,10,10,10,10},
  {2,3,6,10,10,10,10,10},
  {5,7,10,10,10,10,10,10},
  {10,10,10,10,10,10,10,10},
  {10,10,10,10,10,10,10,10},
  {10,10,10,10,10,10,10,10},
  {10,10,10,10,10,10,10,10},
};

// Packed (q, RN(1/q)) tables. Reciprocals computed at compile time with
// IEEE RN semantics (constexpr folding), so the fast-path mul uses exactly
// RN(1/q).
struct F2 { float q, r; };
struct QTab { F2 v[8][8]; };
static constexpr QTab mkq(const float (&b)[8][8]) {
  QTab t{};
  for (int i = 0; i < 8; ++i)
    for (int j = 0; j < 8; ++j) { t.v[i][j].q = b[i][j]; t.v[i][j].r = 1.0f / b[i][j]; }
  return t;
}
static constexpr QTab QLp = mkq(QLt);
static constexpr QTab QCp = mkq(QCt);

// u[k] = sum_j D8[k][j] * x[j]
__device__ __forceinline__ void dct8(const float x[8], float u[8]) {
  #pragma unroll
  for (int k = 0; k < 8; ++k) {
    float a = D8[k][0] * x[0];
    #pragma unroll
    for (int j = 1; j < 8; ++j) a += D8[k][j] * x[j];
    u[k] = a;
  }
}

// u[j] = sum_m x[m] * D8[m][j]
__device__ __forceinline__ void idct8(const float x[8], float u[8]) {
  #pragma unroll
  for (int j = 0; j < 8; ++j) {
    float a = x[0] * D8[0][j];
    #pragma unroll
    for (int m = 1; m < 8; ++m) a += x[m] * D8[m][j];
    u[j] = a;
  }
}

// Bit-exact floor(x / c255) for x in [0,1], c255 = RN(1/255):
// |RN(x*255) - RN(x/c255)| <= 4.8e-5, so when frac(x*255) is > 2e-4 away
// from an integer both floors agree; rare near-boundary lanes take the
// exact IEEE-div branch (execz-skipped in the common case).
__device__ __forceinline__ float to255(float x) {
  const float c255 = (float)(1.0 / 255.0);
  float y  = x * 255.0f;
  float fl = floorf(y);
  float fr = y - fl;                       // exact (Sterbenz / fl==0)
  if (fr < 2e-4f || fr > 1.0f - 2e-4f) {   // rare: resolve exactly
    fl = floorf(x / c255);
  }
  return fminf(fmaxf(fl, 0.0f), 255.0f);
}

// Bit-exact rintf(RN(u/q)): approx quotient via RN(1/q); |t|<=1024 so the
// approx differs from RN(u/q) by <=3.7e-4 — safe unless within 1e-3 of a
// half-integer tie, where we re-do the true division (reproducing the
// reference's double-rounding exactly).
__device__ __forceinline__ float quant_rt(float u, F2 qp) {
  float tq = u * qp.r;
  float n  = rintf(tq);
  float d  = fabsf(tq - n);
  if (d > 0.499f) {                        // rare: near tie
    n = rintf(u / qp.q);
  }
  return n * qp.q;
}

// Tile: 16 rows x 128 cols per block. Grid (W/128=4, H/16=32, B=32), 256 thr.
__global__ __launch_bounds__(256) void jpeg_rt(const float* __restrict__ in,
                                               float* __restrict__ out)
{
  __shared__ __align__(16) float Yp[16][132];
  __shared__ __align__(16) float Cbp[8][68];
  __shared__ __align__(16) float Crp[8][68];
  __shared__ __align__(16) float S1[32][72];
  __shared__ __align__(16) float S2[32][72];
  __shared__ float lut255[256];            // RN(n/255) for n = 0..255

  const int t   = threadIdx.x;
  const int tx  = blockIdx.x;   // 0..3
  const int ty  = blockIdx.y;   // 0..31
  const int img = blockIdx.z;   // 0..31

  const int pr = t >> 5;        // patch row 0..7   (pixel rows 2pr, 2pr+1)
  const int pc = t & 31;        // patch col 0..31  (pixel cols 4pc..4pc+3)

  lut255[t] = (float)t / 255.0f;           // true IEEE div, once per thread

  // ---------------- stage 1: load 2x4 patch, color convert, plane writes
  {
    float yv[2][4];
    float cbv[2][4], crv[2][4];
    #pragma unroll
    for (int rr = 0; rr < 2; ++rr) {
      const size_t grow = (size_t)img * 512 + (size_t)(ty*16 + 2*pr + rr);
      const float* rp = in + (grow*512 + (size_t)(tx*128 + 4*pc))*3;
      float4 A = ((const float4*)rp)[0];
      float4 Bq = ((const float4*)rp)[1];
      float4 Cq = ((const float4*)rp)[2];
      float px[12] = {A.x,A.y,A.z,A.w,Bq.x,Bq.y,Bq.z,Bq.w,Cq.x,Cq.y,Cq.z,Cq.w};
      #pragma unroll
      for (int p = 0; p < 4; ++p) {
        float r = to255(px[3*p+0]);
        float g = to255(px[3*p+1]);
        float b = to255(px[3*p+2]);
        float y  =  0.299f*r + 0.587f*g + 0.114f*b;
        float cb = -0.168736f*r - 0.331264f*g + 0.5f*b + 128.0f;
        float cr =  0.5f*r - 0.418688f*g - 0.081312f*b + 128.0f;
        yv[rr][p]  = y - 128.0f;
        cbv[rr][p] = cb;
        crv[rr][p] = cr;
      }
    }
    *(float4*)&Yp[2*pr+0][4*pc] = make_float4(yv[0][0],yv[0][1],yv[0][2],yv[0][3]);
    *(float4*)&Yp[2*pr+1][4*pc] = make_float4(yv[1][0],yv[1][1],yv[1][2],yv[1][3]);
    float cb0 = ((cbv[0][0]+cbv[0][1]) + (cbv[1][0]+cbv[1][1]))*0.25f - 128.0f;
    float cb1 = ((cbv[0][2]+cbv[0][3]) + (cbv[1][2]+cbv[1][3]))*0.25f - 128.0f;
    float cr0 = ((crv[0][0]+crv[0][1]) + (crv[1][0]+crv[1][1]))*0.25f - 128.0f;
    float cr1 = ((crv[0][2]+crv[0][3]) + (crv[1][2]+crv[1][3]))*0.25f - 128.0f;
    *(float2*)&Cbp[pr][2*pc] = make_float2(cb0, cb1);
    *(float2*)&Crp[pr][2*pc] = make_float2(cr0, cr1);
  }
  __syncthreads();

  // ---------------- luma pass A: row DCT, rows -> S1
  {
    const int b = t >> 3, i = t & 7;
    const int br = b >> 4, bc = b & 15;
    const float* src = &Yp[br*8 + i][bc*8];
    float xr[8], u[8];
    *(float4*)&xr[0] = *(const float4*)&src[0];
    *(float4*)&xr[4] = *(const float4*)&src[4];
    dct8(xr, u);
    *(float4*)&S1[b][i*8+0] = make_float4(u[0],u[1],u[2],u[3]);
    *(float4*)&S1[b][i*8+4] = make_float4(u[4],u[5],u[6],u[7]);
  }
  __syncthreads();

  // ---------------- luma pass B+C: col DCT + quant + row IDCT, rows -> S2
  {
    const int b = t >> 3, kk = t & 7;
    float s[8], u[8], v[8];
    #pragma unroll
    for (int i = 0; i < 8; ++i) s[i] = S1[b][i*8 + kk];
    dct8(s, u);
    #pragma unroll
    for (int m = 0; m < 8; ++m) u[m] = quant_rt(u[m], QLp.v[m][kk]);
    idct8(u, v);
    *(float4*)&S2[b][kk*8+0] = make_float4(v[0],v[1],v[2],v[3]);
    *(float4*)&S2[b][kk*8+4] = make_float4(v[4],v[5],v[6],v[7]);
  }
  __syncthreads();

  // ---------------- luma pass D: col IDCT, rec rows back into Yp
  {
    const int b = t >> 3, j = t & 7;
    float w[8], z[8];
    #pragma unroll
    for (int m = 0; m < 8; ++m) w[m] = S2[b][m*8 + j];
    idct8(w, z);
    const int br = b >> 4, bc = b & 15;
    *(float4*)&Yp[br*8 + j][bc*8 + 0] = make_float4(z[0],z[1],z[2],z[3]);
    *(float4*)&Yp[br*8 + j][bc*8 + 4] = make_float4(z[4],z[5],z[6],z[7]);
  }
  // ---------------- chroma pass A (same phase: S1 free, planes stable)
  if (t < 128) {
    const int b = t >> 3, i = t & 7;          // b: 0..7 Cb, 8..15 Cr
    const float* plane = (b & 8) ? &Crp[0][0] : &Cbp[0][0];
    const float* src = plane + i*68 + (b & 7)*8;
    float xr[8], u[8];
    *(float4*)&xr[0] = *(const float4*)&src[0];
    *(float4*)&xr[4] = *(const float4*)&src[4];
    dct8(xr, u);
    *(float4*)&S1[b][i*8+0] = make_float4(u[0],u[1],u[2],u[3]);
    *(float4*)&S1[b][i*8+4] = make_float4(u[4],u[5],u[6],u[7]);
  }
  __syncthreads();

  // ---------------- chroma pass B+C
  if (t < 128) {
    const int b = t >> 3, kk = t & 7;
    float s[8], u[8], v[8];
    #pragma unroll
    for (int i = 0; i < 8; ++i) s[i] = S1[b][i*8 + kk];
    dct8(s, u);
    #pragma unroll
    for (int m = 0; m < 8; ++m) u[m] = quant_rt(u[m], QCp.v[m][kk]);
    idct8(u, v);
    *(float4*)&S2[b][kk*8+0] = make_float4(v[0],v[1],v[2],v[3]);
    *(float4*)&S2[b][kk*8+4] = make_float4(v[4],v[5],v[6],v[7]);
  }
  __syncthreads();

  // ---------------- chroma pass D: rec rows back into Cb/Cr planes
  if (t < 128) {
    const int b = t >> 3, j = t & 7;
    float w[8], z[8];
    #pragma unroll
    for (int m = 0; m < 8; ++m) w[m] = S2[b][m*8 + j];
    idct8(w, z);
    float* plane = (b & 8) ? &Crp[0][0] : &Cbp[0][0];
    float* dst = plane + j*68 + (b & 7)*8;
    *(float4*)&dst[0] = make_float4(z[0],z[1],z[2],z[3]);
    *(float4*)&dst[4] = make_float4(z[4],z[5],z[6],z[7]);
  }
  __syncthreads();

  // ---------------- output: upsample chroma, YCbCr->RGB, round/clip, LUT /255
  {
    float y0[4], y1[4];
    *(float4*)y0 = *(const float4*)&Yp[2*pr+0][4*pc];
    *(float4*)y1 = *(const float4*)&Yp[2*pr+1][4*pc];
    float2 cbp2 = *(const float2*)&Cbp[pr][2*pc];
    float2 crp2 = *(const float2*)&Crp[pr][2*pc];
    float cbq[2] = {cbp2.x, cbp2.y};
    float crq[2] = {crp2.x, crp2.y};
    #pragma unroll
    for (int rr = 0; rr < 2; ++rr) {
      float ov[12];
      #pragma unroll
      for (int p = 0; p < 4; ++p) {
        float y2  = (rr ? y1[p] : y0[p]) + 128.0f;
        float cb2 = cbq[p>>1] + 128.0f;
        float cr2 = crq[p>>1] + 128.0f;
        float r2 = y2 + 1.402f*(cr2 - 128.0f);
        float g2 = y2 - 0.344136f*(cb2 - 128.0f) - 0.714136f*(cr2 - 128.0f);
        float b2 = y2 + 1.772f*(cb2 - 128.0f);
        ov[3*p+0] = lut255[(int)rintf(fminf(fmaxf(r2, 0.0f), 255.0f))];
        ov[3*p+1] = lut255[(int)rintf(fminf(fmaxf(g2, 0.0f), 255.0f))];
        ov[3*p+2] = lut255[(int)rintf(fminf(fmaxf(b2, 0.0f), 255.0f))];
      }
      const size_t grow = (size_t)img * 512 + (size_t)(ty*16 + 2*pr + rr);
      float* op = out + (grow*512 + (size_t)(tx*128 + 4*pc))*3;
      ((float4*)op)[0] = make_float4(ov[0],ov[1],ov[2],ov[3]);
      ((float4*)op)[1] = make_float4(ov[4],ov[5],ov[6],ov[7]);
      ((float4*)op)[2] = make_float4(ov[8],ov[9],ov[10],ov[11]);
    }
  }
}

extern "C" void kernel_launch(void* const* d_in, const int* in_sizes, int n_in,
                              void* d_out, int out_size, void* d_ws, size_t ws_size,
                              hipStream_t stream) {
  (void)in_sizes; (void)n_in; (void)d_ws; (void)ws_size; (void)out_size;
  const float* x = (const float*)d_in[0];
  float* out = (float*)d_out;
  dim3 grid(4, 32, 32);   // W/128, H/16, B
  jpeg_rt<<<grid, dim3(256), 0, stream>>>(x, out);
}

// Round 3
// 188.042 us; speedup vs baseline: 1.0063x; 1.0063x over previous
//
#include <hip/hip_runtime.h>
#include <cstddef>

// DCT-II matrix (float32 cast of numpy's float64 values)
static constexpr float D8[8][8] = {
  { 0.35355339059327373f, 0.35355339059327373f, 0.35355339059327373f, 0.35355339059327373f,
    0.35355339059327373f, 0.35355339059327373f, 0.35355339059327373f, 0.35355339059327373f},
  { 0.4903926402016152f,  0.4157348061512726f,  0.27778511650980114f, 0.09754516100806417f,
   -0.09754516100806417f,-0.27778511650980114f,-0.4157348061512726f, -0.4903926402016152f},
  { 0.46193976625564337f, 0.19134171618254492f,-0.19134171618254492f,-0.46193976625564337f,
   -0.46193976625564337f,-0.19134171618254492f, 0.19134171618254492f, 0.46193976625564337f},
  { 0.4157348061512726f, -0.09754516100806417f,-0.4903926402016152f, -0.27778511650980114f,
    0.27778511650980114f, 0.4903926402016152f,  0.09754516100806417f,-0.4157348061512726f},
  { 0.35355339059327373f,-0.35355339059327373f,-0.35355339059327373f, 0.35355339059327373f,
    0.35355339059327373f,-0.35355339059327373f,-0.35355339059327373f, 0.35355339059327373f},
  { 0.27778511650980114f,-0.4903926402016152f,  0.09754516100806417f, 0.4157348061512726f,
   -0.4157348061512726f, -0.09754516100806417f, 0.4903926402016152f, -0.27778511650980114f},
  { 0.19134171618254492f,-0.46193976625564337f, 0.46193976625564337f,-0.19134171618254492f,
   -0.19134171618254492f, 0.46193976625564337f,-0.46193976625564337f, 0.19134171618254492f},
  { 0.09754516100806417f,-0.27778511650980114f, 0.4157348061512726f, -0.4903926402016152f,
    0.4903926402016152f, -0.4157348061512726f,  0.27778511650980114f,-0.09754516100806417f},
};

// Quality-95 quant tables: q = clamp(floor((base*10+50)/100), 1, 255)
static constexpr float QLt[8][8] = {
  {2,1,1,2,2,4,5,6},
  {1,1,1,2,3,6,6,6},
  {1,1,2,2,4,6,7,6},
  {1,2,2,3,5,9,8,6},
  {2,2,4,6,7,11,10,8},
  {2,4,6,6,8,10,11,9},
  {5,6,8,9,10,12,12,10},
  {7,9,10,10,11,10,10,10},
};
static constexpr float QCt[8][8] = {
  {2,2,2,5,10,10,10,10},
  {2,2,3,7,10,10,10,10},
  {2,3,6,10,10,10,10,10},
  {5,7,10,10,10,10,10,10},
  {10,10,10,10,10,10,10,10},
  {10,10,10,10,10,10,10,10},
  {10,10,10,10,10,10,10,10},
  {10,10,10,10,10,10,10,10},
};

// Packed (q, RN(1/q)) tables, reciprocal folded at compile time (IEEE RN).
struct F2 { float q, r; };
struct QTab { F2 v[8][8]; };
static constexpr QTab mkq(const float (&b)[8][8]) {
  QTab t{};
  for (int i = 0; i < 8; ++i)
    for (int j = 0; j < 8; ++j) { t.v[i][j].q = b[i][j]; t.v[i][j].r = 1.0f / b[i][j]; }
  return t;
}
static constexpr QTab QLp = mkq(QLt);
static constexpr QTab QCp = mkq(QCt);

__device__ __forceinline__ void dct8(const float x[8], float u[8]) {
  #pragma unroll
  for (int k = 0; k < 8; ++k) {
    float a = D8[k][0] * x[0];
    #pragma unroll
    for (int j = 1; j < 8; ++j) a += D8[k][j] * x[j];
    u[k] = a;
  }
}
__device__ __forceinline__ void idct8(const float x[8], float u[8]) {
  #pragma unroll
  for (int j = 0; j < 8; ++j) {
    float a = x[0] * D8[0][j];
    #pragma unroll
    for (int m = 1; m < 8; ++m) a += x[m] * D8[m][j];
    u[j] = a;
  }
}

// Bit-exact floor(x / RN(1/255)): fast mul path; near-integer lanes (P~4e-4)
// resolve with the true IEEE division.
__device__ __forceinline__ float to255(float x) {
  const float c255 = (float)(1.0 / 255.0);
  float y  = x * 255.0f;
  float fl = floorf(y);
  float fr = y - fl;
  if (__builtin_expect(fr < 2e-4f || fr > 1.0f - 2e-4f, 0)) {
    fl = floorf(x / c255);
  }
  return fminf(fmaxf(fl, 0.0f), 255.0f);
}

// Bit-exact rintf(RN(u/q)): reciprocal-mul path; near-tie lanes (P~2e-3)
// re-do the true division (reproduces reference double-rounding).
__device__ __forceinline__ float quant_rt(float u, F2 qp) {
  float tq = u * qp.r;
  float n  = rintf(tq);
  float d  = fabsf(tq - n);
  if (__builtin_expect(d > 0.499f, 0)) {
    n = rintf(u / qp.q);
  }
  return n * qp.q;
}

// Tile: 16 rows x 128 cols per block. Grid (4,32,32), 256 threads.
// LDS ping-pong: every phase reads one buffer, writes the other.
//   U: [stage1] planes  Y@0 s132 x16 | Cb@2112 s68 x8 | Cr@2656 s68 x8
//      [BC out] S2 dct scratch [48][68]
//   V: [A out]  S1 dct scratch [48][68]
//      [D out]  reconstructed planes, same layout as U-stage1
__global__ __launch_bounds__(256) void jpeg_rt(const float* __restrict__ in,
                                               float* __restrict__ out)
{
  __shared__ __align__(16) float U[3264];
  __shared__ __align__(16) float V[3264];

  const int t   = threadIdx.x;
  const int tx  = blockIdx.x;   // 0..3
  const int ty  = blockIdx.y;   // 0..31
  const int img = blockIdx.z;   // 0..31

  const int pr = t >> 5;        // patch row 0..7   (pixel rows 2pr, 2pr+1)
  const int pc = t & 31;        // patch col 0..31  (pixel cols 4pc..4pc+3)

  float* Yp  = U;               // stride 132
  float* Cbp = U + 2112;        // stride 68
  float* Crp = U + 2656;        // stride 68

  // ---------------- stage 1: load 2x4 patch, color convert -> U planes
  {
    float yv[2][4], cbv[2][4], crv[2][4];
    #pragma unroll
    for (int rr = 0; rr < 2; ++rr) {
      const size_t grow = (size_t)img * 512 + (size_t)(ty*16 + 2*pr + rr);
      const float* rp = in + (grow*512 + (size_t)(tx*128 + 4*pc))*3;
      float4 A = ((const float4*)rp)[0];
      float4 Bq = ((const float4*)rp)[1];
      float4 Cq = ((const float4*)rp)[2];
      float px[12] = {A.x,A.y,A.z,A.w,Bq.x,Bq.y,Bq.z,Bq.w,Cq.x,Cq.y,Cq.z,Cq.w};
      #pragma unroll
      for (int p = 0; p < 4; ++p) {
        float r = to255(px[3*p+0]);
        float g = to255(px[3*p+1]);
        float b = to255(px[3*p+2]);
        float y  =  0.299f*r + 0.587f*g + 0.114f*b;
        float cb = -0.168736f*r - 0.331264f*g + 0.5f*b + 128.0f;
        float cr =  0.5f*r - 0.418688f*g - 0.081312f*b + 128.0f;
        yv[rr][p]  = y - 128.0f;
        cbv[rr][p] = cb;
        crv[rr][p] = cr;
      }
    }
    *(float4*)&Yp[(2*pr+0)*132 + 4*pc] = make_float4(yv[0][0],yv[0][1],yv[0][2],yv[0][3]);
    *(float4*)&Yp[(2*pr+1)*132 + 4*pc] = make_float4(yv[1][0],yv[1][1],yv[1][2],yv[1][3]);
    float cb0 = ((cbv[0][0]+cbv[0][1]) + (cbv[1][0]+cbv[1][1]))*0.25f - 128.0f;
    float cb1 = ((cbv[0][2]+cbv[0][3]) + (cbv[1][2]+cbv[1][3]))*0.25f - 128.0f;
    float cr0 = ((crv[0][0]+crv[0][1]) + (crv[1][0]+crv[1][1]))*0.25f - 128.0f;
    float cr1 = ((crv[0][2]+crv[0][3]) + (crv[1][2]+crv[1][3]))*0.25f - 128.0f;
    *(float2*)&Cbp[pr*68 + 2*pc] = make_float2(cb0, cb1);
    *(float2*)&Crp[pr*68 + 2*pc] = make_float2(cr0, cr1);
  }
  __syncthreads();

  // ---------------- pass A: row DCT for all 48 blocks (384 tasks), U -> V
  #pragma unroll
  for (int task = t; task < 384; task += 256) {
    const int tb = task >> 3, i = task & 7;
    const float* src;
    if (tb < 32)      src = Yp  + (size_t)((tb>>4)*8 + i)*132 + (tb&15)*8;
    else if (tb < 40) src = Cbp + i*68 + (tb-32)*8;
    else              src = Crp + i*68 + (tb-40)*8;
    float xr[8], u[8];
    *(float4*)&xr[0] = *(const float4*)&src[0];
    *(float4*)&xr[4] = *(const float4*)&src[4];
    dct8(xr, u);
    *(float4*)&V[tb*68 + i*8 + 0] = make_float4(u[0],u[1],u[2],u[3]);
    *(float4*)&V[tb*68 + i*8 + 4] = make_float4(u[4],u[5],u[6],u[7]);
  }
  __syncthreads();

  // ---------------- pass B+C: col DCT + quant + col IDCT, V -> U
  #pragma unroll
  for (int task = t; task < 384; task += 256) {
    const int tb = task >> 3, kk = task & 7;
    float s[8], u[8], v[8];
    #pragma unroll
    for (int i = 0; i < 8; ++i) s[i] = V[tb*68 + i*8 + kk];
    dct8(s, u);
    if (tb < 32) {
      #pragma unroll
      for (int m = 0; m < 8; ++m) u[m] = quant_rt(u[m], QLp.v[m][kk]);
    } else {
      #pragma unroll
      for (int m = 0; m < 8; ++m) u[m] = quant_rt(u[m], QCp.v[m][kk]);
    }
    idct8(u, v);
    *(float4*)&U[tb*68 + kk*8 + 0] = make_float4(v[0],v[1],v[2],v[3]);
    *(float4*)&U[tb*68 + kk*8 + 4] = make_float4(v[4],v[5],v[6],v[7]);
  }
  __syncthreads();

  // ---------------- pass D: row IDCT, U -> V as reconstructed planes
  float* Yr  = V;
  float* Cbr = V + 2112;
  float* Crr = V + 2656;
  #pragma unroll
  for (int task = t; task < 384; task += 256) {
    const int tb = task >> 3, j = task & 7;
    float w[8], z[8];
    #pragma unroll
    for (int m = 0; m < 8; ++m) w[m] = U[tb*68 + m*8 + j];
    idct8(w, z);
    float* dst;
    if (tb < 32)      dst = Yr  + (size_t)((tb>>4)*8 + j)*132 + (tb&15)*8;
    else if (tb < 40) dst = Cbr + j*68 + (tb-32)*8;
    else              dst = Crr + j*68 + (tb-40)*8;
    *(float4*)&dst[0] = make_float4(z[0],z[1],z[2],z[3]);
    *(float4*)&dst[4] = make_float4(z[4],z[5],z[6],z[7]);
  }
  __syncthreads();

  // ---------------- output: upsample chroma, YCbCr->RGB, round/clip, *(1/255)
  {
    const float c255 = (float)(1.0 / 255.0);  // <=1 ulp vs true div; no
                                              // rounding decision downstream
    float y0[4], y1[4];
    *(float4*)y0 = *(const float4*)&Yr[(2*pr+0)*132 + 4*pc];
    *(float4*)y1 = *(const float4*)&Yr[(2*pr+1)*132 + 4*pc];
    float2 cbp2 = *(const float2*)&Cbr[pr*68 + 2*pc];
    float2 crp2 = *(const float2*)&Crr[pr*68 + 2*pc];
    float cbq[2] = {cbp2.x, cbp2.y};
    float crq[2] = {crp2.x, crp2.y};
    #pragma unroll
    for (int rr = 0; rr < 2; ++rr) {
      float ov[12];
      #pragma unroll
      for (int p = 0; p < 4; ++p) {
        float y2  = (rr ? y1[p] : y0[p]) + 128.0f;
        float cb2 = cbq[p>>1] + 128.0f;
        float cr2 = crq[p>>1] + 128.0f;
        float r2 = y2 + 1.402f*(cr2 - 128.0f);
        float g2 = y2 - 0.344136f*(cb2 - 128.0f) - 0.714136f*(cr2 - 128.0f);
        float b2 = y2 + 1.772f*(cb2 - 128.0f);
        ov[3*p+0] = rintf(fminf(fmaxf(r2, 0.0f), 255.0f)) * c255;
        ov[3*p+1] = rintf(fminf(fmaxf(g2, 0.0f), 255.0f)) * c255;
        ov[3*p+2] = rintf(fminf(fmaxf(b2, 0.0f), 255.0f)) * c255;
      }
      const size_t grow = (size_t)img * 512 + (size_t)(ty*16 + 2*pr + rr);
      float* op = out + (grow*512 + (size_t)(tx*128 + 4*pc))*3;
      ((float4*)op)[0] = make_float4(ov[0],ov[1],ov[2],ov[3]);
      ((float4*)op)[1] = make_float4(ov[4],ov[5],ov[6],ov[7]);
      ((float4*)op)[2] = make_float4(ov[8],ov[9],ov[10],ov[11]);
    }
  }
}

extern "C" void kernel_launch(void* const* d_in, const int* in_sizes, int n_in,
                              void* d_out, int out_size, void* d_ws, size_t ws_size,
                              hipStream_t stream) {
  (void)in_sizes; (void)n_in; (void)d_ws; (void)ws_size; (void)out_size;
  const float* x = (const float*)d_in[0];
  float* out = (float*)d_out;
  dim3 grid(4, 32, 32);   // W/128, H/16, B
  jpeg_rt<<<grid, dim3(256), 0, stream>>>(x, out);
}